// Round 4
// baseline (405.500 us; speedup 1.0000x reference)
//
#include <hip/hip_runtime.h>
#include <hip/hip_bf16.h>

#define D 128

typedef __attribute__((ext_vector_type(8))) short bf16x8;
typedef __attribute__((ext_vector_type(4))) float f32x4;
typedef unsigned short u16;
typedef unsigned int u32;

// fp32 -> bf16 round-to-nearest-even, bit-level
__device__ inline u16 f2bf(float f) {
    union { float f; u32 u; } v; v.f = f;
    u32 r = v.u + 0x7FFFu + ((v.u >> 16) & 1u);
    return (u16)(r >> 16);
}

// ---------------------------------------------------------------------------
// fp32 -> bf16 cast, 4 elements/thread
// ---------------------------------------------------------------------------
__global__ void cast_kernel(const float* __restrict__ in, u16* __restrict__ out, int n4) {
    int i = blockIdx.x * blockDim.x + threadIdx.x;
    if (i < n4) {
        float4 v = *(const float4*)(in + (size_t)i * 4);
        u32 lo = (u32)f2bf(v.x) | ((u32)f2bf(v.y) << 16);
        u32 hi = (u32)f2bf(v.z) | ((u32)f2bf(v.w) << 16);
        *(uint2*)(out + (size_t)i * 4) = make_uint2(lo, hi);
    }
}

// ---------------------------------------------------------------------------
// CSR build: histogram of src, scan -> rowptr, bucket-fill packed (dst,w).
// ---------------------------------------------------------------------------
__global__ void hist_kernel(const int* __restrict__ src, int* __restrict__ deg, int E) {
    int i = blockIdx.x * blockDim.x + threadIdx.x;
    if (i < E) atomicAdd(&deg[src[i]], 1);
}

__global__ void scan1_kernel(const int* __restrict__ deg, int* __restrict__ rowptr,
                             int* __restrict__ bsum, int n) {
    __shared__ int s[1024];
    int t = threadIdx.x;
    int i = blockIdx.x * 1024 + t;
    int v = (i < n) ? deg[i] : 0;
    s[t] = v;
    __syncthreads();
    for (int off = 1; off < 1024; off <<= 1) {
        int x = (t >= off) ? s[t - off] : 0;
        __syncthreads();
        s[t] += x;
        __syncthreads();
    }
    if (i < n) rowptr[i + 1] = s[t];
    if (t == 1023) bsum[blockIdx.x] = s[t];
}

__global__ void scan2_kernel(int* __restrict__ bsum, int nb) {
    __shared__ int s[1024];
    int t = threadIdx.x;
    int v = (t < nb) ? bsum[t] : 0;
    s[t] = v;
    __syncthreads();
    for (int off = 1; off < 1024; off <<= 1) {
        int x = (t >= off) ? s[t - off] : 0;
        __syncthreads();
        s[t] += x;
        __syncthreads();
    }
    if (t < nb) bsum[t] = (t == 0) ? 0 : s[t - 1];
}

__global__ void scan3_kernel(const int* __restrict__ deg, const int* __restrict__ bsum,
                             int* __restrict__ rowptr, int* __restrict__ cursor, int n) {
    int i = blockIdx.x * blockDim.x + threadIdx.x;
    if (i < n) {
        int v = rowptr[i + 1] + bsum[i >> 10];
        rowptr[i + 1] = v;
        cursor[i] = v - deg[i];
    }
    if (i == 0) rowptr[0] = 0;
}

// Packed edge record: .x = dst node, .y = fp32 weight bits. One 8B store/edge.
__global__ void fill_kernel(const int* __restrict__ src, const int* __restrict__ dst,
                            const float* __restrict__ w, int* __restrict__ cursor,
                            uint2* __restrict__ edge, int E) {
    int i = blockIdx.x * blockDim.x + threadIdx.x;
    if (i < E) {
        int p = atomicAdd(&cursor[src[i]], 1);
        edge[p] = make_uint2((u32)dst[i], __float_as_uint(w[i]));
    }
}

// ---------------------------------------------------------------------------
// Gather aggregation (bf16 features): one wave per node; lane holds 2 feats.
// neigh[node] = bf16( sum_e w_e*feat[dst_e] / max(sum_e w_e, eps) )
// ---------------------------------------------------------------------------
__global__ void aggregate_kernel(const u16* __restrict__ feat,
                                 const int* __restrict__ rowptr,
                                 const uint2* __restrict__ edge,
                                 u16* __restrict__ neigh, int n) {
    int node = blockIdx.x * 4 + (threadIdx.x >> 6);
    if (node >= n) return;
    int lane = threadIdx.x & 63;
    int beg = rowptr[node];
    int end = rowptr[node + 1];
    float ax = 0.f, ay = 0.f, ws = 0.f;
    int j = beg;
    for (; j + 3 < end; j += 4) {   // 4 gathers in flight
        uint2 e0 = edge[j], e1 = edge[j + 1], e2 = edge[j + 2], e3 = edge[j + 3];
        float w0 = __uint_as_float(e0.y), w1 = __uint_as_float(e1.y);
        float w2 = __uint_as_float(e2.y), w3 = __uint_as_float(e3.y);
        u32 u0 = *(const u32*)(feat + (size_t)e0.x * D + lane * 2);
        u32 u1 = *(const u32*)(feat + (size_t)e1.x * D + lane * 2);
        u32 u2 = *(const u32*)(feat + (size_t)e2.x * D + lane * 2);
        u32 u3 = *(const u32*)(feat + (size_t)e3.x * D + lane * 2);
        ax += __uint_as_float(u0 << 16) * w0 + __uint_as_float(u1 << 16) * w1
            + __uint_as_float(u2 << 16) * w2 + __uint_as_float(u3 << 16) * w3;
        ay += __uint_as_float(u0 & 0xFFFF0000u) * w0 + __uint_as_float(u1 & 0xFFFF0000u) * w1
            + __uint_as_float(u2 & 0xFFFF0000u) * w2 + __uint_as_float(u3 & 0xFFFF0000u) * w3;
        ws += w0 + w1 + w2 + w3;
    }
    for (; j < end; ++j) {
        uint2 e0 = edge[j];
        float w0 = __uint_as_float(e0.y);
        u32 u0 = *(const u32*)(feat + (size_t)e0.x * D + lane * 2);
        ax += __uint_as_float(u0 << 16) * w0;
        ay += __uint_as_float(u0 & 0xFFFF0000u) * w0;
        ws += w0;
    }
    float inv = 1.0f / fmaxf(ws, 1e-12f);
    u32 o = (u32)f2bf(ax * inv) | ((u32)f2bf(ay * inv) << 16);
    *(u32*)(neigh + (size_t)node * D + lane * 2) = o;
}

// ---------------------------------------------------------------------------
// Fused SAGE GEMM, all-bf16 inputs. 256x128 tile/block, 512 threads (8 waves).
// A[r][k] = axb[r][k] (k<128) else aneigh[r][k-128]. Wb is bf16 [128][256].
// Register-prefetch double buffering: global loads for chunk kc+1 issue while
// MFMAs consume chunk kc from LDS.
// NORM=false: store bf16 h.  NORM=true: row-L2-normalize in-epilogue, store f32.
// ---------------------------------------------------------------------------
template <bool NORM>
__global__ void __launch_bounds__(512, 4)
sage_gemm(const u16* __restrict__ axb,
          const u16* __restrict__ aneigh,
          const u16* __restrict__ Wb,      // [128][256] bf16
          const float* __restrict__ bias,  // [128]
          u16* __restrict__ outB,          // NORM=false
          float* __restrict__ outF,        // NORM=true
          int n) {
    __shared__ short As[256][72];   // 36.9 KB; +8 pad keeps aliasing 2-way (free)
    __shared__ short Bs[128][72];   // 18.4 KB

    const int row0 = blockIdx.x * 256;
    const int tid  = threadIdx.x;
    const int wave = tid >> 6;   // 0..7
    const int lane = tid & 63;
    const int quad = lane >> 4;
    const int l16  = lane & 15;

    f32x4 acc[2][8];
#pragma unroll
    for (int rt = 0; rt < 2; ++rt)
#pragma unroll
        for (int c = 0; c < 8; ++c)
            acc[rt][c] = (f32x4){0.f, 0.f, 0.f, 0.f};

    uint4 pa[4], pb[2];
    auto loadTile = [&](int kc) {
        const u16* asrc = (kc >= 2) ? aneigh : axb;
        const int cbase = (kc & 1) * 64;
#pragma unroll
        for (int i = 0; i < 4; ++i) {
            int e = i * 512 + tid;          // 0..2047 -> 256 rows x 8 chunks
            int r = e >> 3;
            int c8 = (e & 7) * 8;
            int row = row0 + r;
            if (row >= n) row = n - 1;       // clamp; garbage rows never stored
            pa[i] = *(const uint4*)(asrc + (size_t)row * D + cbase + c8);
        }
#pragma unroll
        for (int i = 0; i < 2; ++i) {
            int e = i * 512 + tid;          // 0..1023 -> 128 rows x 8 chunks
            int r = e >> 3;
            int c8 = (e & 7) * 8;
            pb[i] = *(const uint4*)(Wb + (size_t)r * 256 + kc * 64 + c8);
        }
    };

    loadTile(0);
#pragma unroll
    for (int kc = 0; kc < 4; ++kc) {
        // commit prefetched chunk to LDS
#pragma unroll
        for (int i = 0; i < 4; ++i) {
            int e = i * 512 + tid;
            *(uint4*)(&As[e >> 3][(e & 7) * 8]) = pa[i];
        }
#pragma unroll
        for (int i = 0; i < 2; ++i) {
            int e = i * 512 + tid;
            *(uint4*)(&Bs[e >> 3][(e & 7) * 8]) = pb[i];
        }
        __syncthreads();
        if (kc < 3) loadTile(kc + 1);   // overlaps with MFMA below

#pragma unroll
        for (int ks = 0; ks < 2; ++ks) {
            const int koff = ks * 32 + quad * 8;
            bf16x8 a0 = *(const bf16x8*)&As[wave * 32 + l16][koff];
            bf16x8 a1 = *(const bf16x8*)&As[wave * 32 + 16 + l16][koff];
#pragma unroll
            for (int c = 0; c < 8; ++c) {
                bf16x8 b = *(const bf16x8*)&Bs[c * 16 + l16][koff];
                acc[0][c] = __builtin_amdgcn_mfma_f32_16x16x32_bf16(a0, b, acc[0][c], 0, 0, 0);
                acc[1][c] = __builtin_amdgcn_mfma_f32_16x16x32_bf16(a1, b, acc[1][c], 0, 0, 0);
            }
        }
        __syncthreads();
    }

    // Epilogue. C/D layout: col=lane&15, row=quad*4+reg.
    float bvals[8];
#pragma unroll
    for (int c = 0; c < 8; ++c) bvals[c] = bias[c * 16 + l16];

#pragma unroll
    for (int rt = 0; rt < 2; ++rt) {
#pragma unroll
        for (int reg = 0; reg < 4; ++reg) {
            int row = row0 + wave * 32 + rt * 16 + quad * 4 + reg;
            if (row >= n) continue;
            float v[8];
#pragma unroll
            for (int c = 0; c < 8; ++c)
                v[c] = fmaxf(acc[rt][c][reg] + bvals[c], 0.0f);
            if (NORM) {
                // row lives in the 16 lanes of this quad (l16=0..15), 8 vals each
                float ss = 0.f;
#pragma unroll
                for (int c = 0; c < 8; ++c) ss += v[c] * v[c];
                ss += __shfl_xor(ss, 1);
                ss += __shfl_xor(ss, 2);
                ss += __shfl_xor(ss, 4);
                ss += __shfl_xor(ss, 8);
                float inv = 1.0f / fmaxf(sqrtf(ss), 1e-12f);
                float* orow = outF + (size_t)row * D;
#pragma unroll
                for (int c = 0; c < 8; ++c)
                    orow[c * 16 + l16] = v[c] * inv;
            } else {
                u16* orow = outB + (size_t)row * D;
#pragma unroll
                for (int c = 0; c < 8; ++c)
                    orow[c * 16 + l16] = f2bf(v[c]);
            }
        }
    }
}

extern "C" void kernel_launch(void* const* d_in, const int* in_sizes, int n_in,
                              void* d_out, int out_size, void* d_ws, size_t ws_size,
                              hipStream_t stream) {
    const float* x  = (const float*)d_in[0];
    const int*   ei = (const int*)d_in[1];   // [2, E]: row 0 = src, row 1 = dst
    const float* ew = (const float*)d_in[2];
    const float* W1 = (const float*)d_in[3];
    const float* b1 = (const float*)d_in[4];
    const float* W2 = (const float*)d_in[5];
    const float* b2 = (const float*)d_in[6];
    float* out = (float*)d_out;

    const int E = in_sizes[2];
    const int N = in_sizes[0] / D;

    const int* src = ei;
    const int* dst = ei + E;

    // workspace layout
    char* p = (char*)d_ws;
    auto alloc = [&](size_t bytes) { char* r = p; p += (bytes + 255) & ~(size_t)255; return r; };
    u16*   xb     = (u16*)  alloc((size_t)N * D * sizeof(u16));   // 25.6 MB
    u16*   hB     = (u16*)  alloc((size_t)N * D * sizeof(u16));   // 25.6 MB
    u16*   neighB = (u16*)  alloc((size_t)N * D * sizeof(u16));   // 25.6 MB
    uint2* edge   = (uint2*)alloc((size_t)E * sizeof(uint2));     // 6.4 MB
    u16*   Wb1    = (u16*)  alloc((size_t)D * 2 * D * sizeof(u16));
    u16*   Wb2    = (u16*)  alloc((size_t)D * 2 * D * sizeof(u16));
    int*   rowptr = (int*)  alloc((size_t)(N + 1) * sizeof(int));
    int*   deg    = (int*)  alloc((size_t)N * sizeof(int));
    int*   cursor = (int*)  alloc((size_t)N * sizeof(int));
    int*   bsum   = (int*)  alloc(1024 * sizeof(int));

    const int NB = (N + 1023) / 1024;
    const int gemmGrid = (N + 255) / 256;
    const int n4 = N * D / 4;
    const int w4 = D * 2 * D / 4;   // 8192

    // ---- CSR build + casts ----
    hipMemsetAsync(deg, 0, (size_t)N * sizeof(int), stream);
    hist_kernel <<<(E + 255) / 256, 256, 0, stream>>>(src, deg, E);
    scan1_kernel<<<NB, 1024, 0, stream>>>(deg, rowptr, bsum, N);
    scan2_kernel<<<1, 1024, 0, stream>>>(bsum, NB);
    scan3_kernel<<<(N + 255) / 256, 256, 0, stream>>>(deg, bsum, rowptr, cursor, N);
    fill_kernel <<<(E + 255) / 256, 256, 0, stream>>>(src, dst, ew, cursor, edge, E);
    cast_kernel <<<(n4 + 255) / 256, 256, 0, stream>>>(x, xb, n4);
    cast_kernel <<<(w4 + 255) / 256, 256, 0, stream>>>(W1, Wb1, w4);
    cast_kernel <<<(w4 + 255) / 256, 256, 0, stream>>>(W2, Wb2, w4);

    // ---- Layer 1 ----
    aggregate_kernel<<<(N + 3) / 4, 256, 0, stream>>>(xb, rowptr, edge, neighB, N);
    sage_gemm<false><<<gemmGrid, 512, 0, stream>>>(xb, neighB, Wb1, b1, hB, nullptr, N);

    // ---- Layer 2 (normalize fused into epilogue) ----
    aggregate_kernel<<<(N + 3) / 4, 256, 0, stream>>>(hB, rowptr, edge, neighB, N);
    sage_gemm<true><<<gemmGrid, 512, 0, stream>>>(hB, neighB, Wb2, b2, nullptr, out, N);
}

// Round 5
// 364.477 us; speedup vs baseline: 1.1126x; 1.1126x over previous
//
#include <hip/hip_runtime.h>
#include <hip/hip_bf16.h>

#define D 128
#define BSH 8                      // 256 nodes per bucket
#define BMASK 255

typedef __attribute__((ext_vector_type(8))) short bf16x8;
typedef __attribute__((ext_vector_type(4))) float f32x4;
typedef unsigned short u16;
typedef unsigned int u32;

// fp32 -> bf16 round-to-nearest-even, bit-level
__device__ inline u16 f2bf(float f) {
    union { float f; u32 u; } v; v.f = f;
    u32 r = v.u + 0x7FFFu + ((v.u >> 16) & 1u);
    return (u16)(r >> 16);
}

// ---------------------------------------------------------------------------
// fp32 -> bf16 cast, 4 elements/thread
// ---------------------------------------------------------------------------
__global__ void cast_kernel(const float* __restrict__ in, u16* __restrict__ out, int n4) {
    int i = blockIdx.x * blockDim.x + threadIdx.x;
    if (i < n4) {
        float4 v = *(const float4*)(in + (size_t)i * 4);
        u32 lo = (u32)f2bf(v.x) | ((u32)f2bf(v.y) << 16);
        u32 hi = (u32)f2bf(v.z) | ((u32)f2bf(v.w) << 16);
        *(uint2*)(out + (size_t)i * 4) = make_uint2(lo, hi);
    }
}

// ---------------------------------------------------------------------------
// Two-level bucketed CSR build. Bucket = 256 consecutive src nodes.
// Stage 1: per-block LDS histogram -> one global atomic per (block,bucket).
// ---------------------------------------------------------------------------
__global__ void bucket_count(const int* __restrict__ src, int* __restrict__ bucketCount,
                             int E, int nbuk) {
    __shared__ int cnt[1024];
    for (int i = threadIdx.x; i < nbuk; i += blockDim.x) cnt[i] = 0;
    __syncthreads();
    int stride = gridDim.x * blockDim.x;
    for (int i = blockIdx.x * blockDim.x + threadIdx.x; i < E; i += stride)
        atomicAdd(&cnt[src[i] >> BSH], 1);
    __syncthreads();
    for (int i = threadIdx.x; i < nbuk; i += blockDim.x)
        if (cnt[i]) atomicAdd(&bucketCount[i], cnt[i]);
}

// Stage 2: exclusive scan of bucket counts (nbuk <= 1023). One block.
__global__ void bucket_scan(const int* __restrict__ bucketCount, int* __restrict__ bucketBase,
                            int* __restrict__ bucketCursor, int nbuk, int E) {
    __shared__ int s[1024];
    int t = threadIdx.x;
    s[t] = (t < nbuk) ? bucketCount[t] : 0;
    __syncthreads();
    for (int off = 1; off < 1024; off <<= 1) {
        int v = (t >= off) ? s[t - off] : 0;
        __syncthreads();
        s[t] += v;
        __syncthreads();
    }
    if (t < nbuk) {
        int excl = (t == 0) ? 0 : s[t - 1];
        bucketBase[t] = excl;
        bucketCursor[t] = excl;
    }
    if (t == 0) bucketBase[nbuk] = E;
}

// Stage 3: partition edges into buckets. Each block two-passes its chunk:
// LDS hist -> bulk reservation (1 global atomic per bucket) -> LDS-cursor
// scatter into per-(block,bucket) runs. Record: .x = dst | srcLocal<<17
// (valid for N < 131072), .y = weight bits.
__global__ void partition_kernel(const int* __restrict__ src, const int* __restrict__ dst,
                                 const float* __restrict__ w, int* __restrict__ bucketCursor,
                                 uint2* __restrict__ temp, int E, int nbuk) {
    __shared__ int cnt[1024];
    __shared__ int base[1024];
    int per = (E + gridDim.x - 1) / gridDim.x;
    int lo = blockIdx.x * per;
    int hi = min(E, lo + per);
    for (int i = threadIdx.x; i < nbuk; i += blockDim.x) cnt[i] = 0;
    __syncthreads();
    for (int i = lo + threadIdx.x; i < hi; i += blockDim.x)
        atomicAdd(&cnt[src[i] >> BSH], 1);
    __syncthreads();
    for (int i = threadIdx.x; i < nbuk; i += blockDim.x)
        base[i] = cnt[i] ? atomicAdd(&bucketCursor[i], cnt[i]) : 0;
    __syncthreads();
    for (int i = threadIdx.x; i < nbuk; i += blockDim.x) cnt[i] = 0;
    __syncthreads();
    for (int i = lo + threadIdx.x; i < hi; i += blockDim.x) {
        int s = src[i];
        int b = s >> BSH;
        int off = atomicAdd(&cnt[b], 1);
        temp[base[b] + off] =
            make_uint2((u32)dst[i] | ((u32)(s & BMASK) << 17), __float_as_uint(w[i]));
    }
}

// Stage 4: per-bucket CSR finalize. One block per bucket. Local deg+scan in
// LDS replaces the global histogram/scan; scatter is confined to the bucket's
// ~16KB window (block-private -> full-line writebacks).
__global__ void bucket_csr(const uint2* __restrict__ temp, const int* __restrict__ bucketBase,
                           int* __restrict__ rowptr, uint2* __restrict__ edge,
                           int N, int E) {
    int b = blockIdx.x;
    int lo = bucketBase[b], hi = bucketBase[b + 1];
    int t = threadIdx.x;
    __shared__ int deg_l[256];
    __shared__ int sc[256];
    __shared__ int cur[256];
    deg_l[t] = 0;
    __syncthreads();
    for (int i = lo + t; i < hi; i += 256)
        atomicAdd(&deg_l[temp[i].x >> 17], 1);
    __syncthreads();
    sc[t] = deg_l[t];
    __syncthreads();
    for (int off = 1; off < 256; off <<= 1) {
        int v = (t >= off) ? sc[t - off] : 0;
        __syncthreads();
        sc[t] += v;
        __syncthreads();
    }
    int excl = (t == 0) ? 0 : sc[t - 1];
    int gnode = b * 256 + t;
    if (gnode < N) rowptr[gnode] = lo + excl;
    if (b == 0 && t == 0) rowptr[N] = E;
    cur[t] = excl;
    __syncthreads();
    for (int i = lo + t; i < hi; i += 256) {
        uint2 r = temp[i];                     // L2-hot (read moments ago)
        int p = atomicAdd(&cur[r.x >> 17], 1);
        edge[lo + p] = make_uint2(r.x & 0x1FFFFu, r.y);
    }
}

// ---------------------------------------------------------------------------
// Gather aggregation (bf16 features): one wave per node; lane holds 2 feats.
// neigh[node] = bf16( sum_e w_e*feat[dst_e] / max(sum_e w_e, eps) )
// ---------------------------------------------------------------------------
__global__ void aggregate_kernel(const u16* __restrict__ feat,
                                 const int* __restrict__ rowptr,
                                 const uint2* __restrict__ edge,
                                 u16* __restrict__ neigh, int n) {
    int node = blockIdx.x * 4 + (threadIdx.x >> 6);
    if (node >= n) return;
    int lane = threadIdx.x & 63;
    int beg = rowptr[node];
    int end = rowptr[node + 1];
    float ax = 0.f, ay = 0.f, ws = 0.f;
    int j = beg;
    for (; j + 3 < end; j += 4) {   // 4 gathers in flight
        uint2 e0 = edge[j], e1 = edge[j + 1], e2 = edge[j + 2], e3 = edge[j + 3];
        float w0 = __uint_as_float(e0.y), w1 = __uint_as_float(e1.y);
        float w2 = __uint_as_float(e2.y), w3 = __uint_as_float(e3.y);
        u32 u0 = *(const u32*)(feat + (size_t)e0.x * D + lane * 2);
        u32 u1 = *(const u32*)(feat + (size_t)e1.x * D + lane * 2);
        u32 u2 = *(const u32*)(feat + (size_t)e2.x * D + lane * 2);
        u32 u3 = *(const u32*)(feat + (size_t)e3.x * D + lane * 2);
        ax += __uint_as_float(u0 << 16) * w0 + __uint_as_float(u1 << 16) * w1
            + __uint_as_float(u2 << 16) * w2 + __uint_as_float(u3 << 16) * w3;
        ay += __uint_as_float(u0 & 0xFFFF0000u) * w0 + __uint_as_float(u1 & 0xFFFF0000u) * w1
            + __uint_as_float(u2 & 0xFFFF0000u) * w2 + __uint_as_float(u3 & 0xFFFF0000u) * w3;
        ws += w0 + w1 + w2 + w3;
    }
    for (; j < end; ++j) {
        uint2 e0 = edge[j];
        float w0 = __uint_as_float(e0.y);
        u32 u0 = *(const u32*)(feat + (size_t)e0.x * D + lane * 2);
        ax += __uint_as_float(u0 << 16) * w0;
        ay += __uint_as_float(u0 & 0xFFFF0000u) * w0;
        ws += w0;
    }
    float inv = 1.0f / fmaxf(ws, 1e-12f);
    u32 o = (u32)f2bf(ax * inv) | ((u32)f2bf(ay * inv) << 16);
    *(u32*)(neigh + (size_t)node * D + lane * 2) = o;
}

// ---------------------------------------------------------------------------
// Fused SAGE GEMM, all-bf16 inputs. 256x128 tile/block, 512 threads (8 waves).
// A[r][k] = axb[r][k] (k<128) else aneigh[r][k-128]. Wb is bf16 [128][256].
// Register-prefetch double buffering.
// NORM=false: store bf16 h.  NORM=true: row-L2-normalize in-epilogue, store f32.
// ---------------------------------------------------------------------------
template <bool NORM>
__global__ void __launch_bounds__(512, 4)
sage_gemm(const u16* __restrict__ axb,
          const u16* __restrict__ aneigh,
          const u16* __restrict__ Wb,      // [128][256] bf16
          const float* __restrict__ bias,  // [128]
          u16* __restrict__ outB,          // NORM=false
          float* __restrict__ outF,        // NORM=true
          int n) {
    __shared__ short As[256][72];   // +8 pad keeps aliasing 2-way (free)
    __shared__ short Bs[128][72];

    const int row0 = blockIdx.x * 256;
    const int tid  = threadIdx.x;
    const int wave = tid >> 6;   // 0..7
    const int lane = tid & 63;
    const int quad = lane >> 4;
    const int l16  = lane & 15;

    f32x4 acc[2][8];
#pragma unroll
    for (int rt = 0; rt < 2; ++rt)
#pragma unroll
        for (int c = 0; c < 8; ++c)
            acc[rt][c] = (f32x4){0.f, 0.f, 0.f, 0.f};

    uint4 pa[4], pb[2];
    auto loadTile = [&](int kc) {
        const u16* asrc = (kc >= 2) ? aneigh : axb;
        const int cbase = (kc & 1) * 64;
#pragma unroll
        for (int i = 0; i < 4; ++i) {
            int e = i * 512 + tid;
            int r = e >> 3;
            int c8 = (e & 7) * 8;
            int row = row0 + r;
            if (row >= n) row = n - 1;       // clamp; garbage rows never stored
            pa[i] = *(const uint4*)(asrc + (size_t)row * D + cbase + c8);
        }
#pragma unroll
        for (int i = 0; i < 2; ++i) {
            int e = i * 512 + tid;
            int r = e >> 3;
            int c8 = (e & 7) * 8;
            pb[i] = *(const uint4*)(Wb + (size_t)r * 256 + kc * 64 + c8);
        }
    };

    loadTile(0);
#pragma unroll
    for (int kc = 0; kc < 4; ++kc) {
#pragma unroll
        for (int i = 0; i < 4; ++i) {
            int e = i * 512 + tid;
            *(uint4*)(&As[e >> 3][(e & 7) * 8]) = pa[i];
        }
#pragma unroll
        for (int i = 0; i < 2; ++i) {
            int e = i * 512 + tid;
            *(uint4*)(&Bs[e >> 3][(e & 7) * 8]) = pb[i];
        }
        __syncthreads();
        if (kc < 3) loadTile(kc + 1);   // overlaps with MFMA below

#pragma unroll
        for (int ks = 0; ks < 2; ++ks) {
            const int koff = ks * 32 + quad * 8;
            bf16x8 a0 = *(const bf16x8*)&As[wave * 32 + l16][koff];
            bf16x8 a1 = *(const bf16x8*)&As[wave * 32 + 16 + l16][koff];
#pragma unroll
            for (int c = 0; c < 8; ++c) {
                bf16x8 b = *(const bf16x8*)&Bs[c * 16 + l16][koff];
                acc[0][c] = __builtin_amdgcn_mfma_f32_16x16x32_bf16(a0, b, acc[0][c], 0, 0, 0);
                acc[1][c] = __builtin_amdgcn_mfma_f32_16x16x32_bf16(a1, b, acc[1][c], 0, 0, 0);
            }
        }
        __syncthreads();
    }

    // Epilogue. C/D layout: col=lane&15, row=quad*4+reg.
    float bvals[8];
#pragma unroll
    for (int c = 0; c < 8; ++c) bvals[c] = bias[c * 16 + l16];

#pragma unroll
    for (int rt = 0; rt < 2; ++rt) {
#pragma unroll
        for (int reg = 0; reg < 4; ++reg) {
            int row = row0 + wave * 32 + rt * 16 + quad * 4 + reg;
            if (row >= n) continue;
            float v[8];
#pragma unroll
            for (int c = 0; c < 8; ++c)
                v[c] = fmaxf(acc[rt][c][reg] + bvals[c], 0.0f);
            if (NORM) {
                float ss = 0.f;
#pragma unroll
                for (int c = 0; c < 8; ++c) ss += v[c] * v[c];
                ss += __shfl_xor(ss, 1);
                ss += __shfl_xor(ss, 2);
                ss += __shfl_xor(ss, 4);
                ss += __shfl_xor(ss, 8);
                float inv = 1.0f / fmaxf(sqrtf(ss), 1e-12f);
                float* orow = outF + (size_t)row * D;
#pragma unroll
                for (int c = 0; c < 8; ++c)
                    orow[c * 16 + l16] = v[c] * inv;
            } else {
                u16* orow = outB + (size_t)row * D;
#pragma unroll
                for (int c = 0; c < 8; ++c)
                    orow[c * 16 + l16] = f2bf(v[c]);
            }
        }
    }
}

extern "C" void kernel_launch(void* const* d_in, const int* in_sizes, int n_in,
                              void* d_out, int out_size, void* d_ws, size_t ws_size,
                              hipStream_t stream) {
    const float* x  = (const float*)d_in[0];
    const int*   ei = (const int*)d_in[1];   // [2, E]: row 0 = src, row 1 = dst
    const float* ew = (const float*)d_in[2];
    const float* W1 = (const float*)d_in[3];
    const float* b1 = (const float*)d_in[4];
    const float* W2 = (const float*)d_in[5];
    const float* b2 = (const float*)d_in[6];
    float* out = (float*)d_out;

    const int E = in_sizes[2];
    const int N = in_sizes[0] / D;
    const int nbuk = (N + 255) >> BSH;       // 391 for N=100000 (< 1024 required)

    const int* src = ei;
    const int* dst = ei + E;

    // workspace layout
    char* p = (char*)d_ws;
    auto alloc = [&](size_t bytes) { char* r = p; p += (bytes + 255) & ~(size_t)255; return r; };
    u16*   xb      = (u16*)  alloc((size_t)N * D * sizeof(u16));   // 25.6 MB
    u16*   hB      = (u16*)  alloc((size_t)N * D * sizeof(u16));   // 25.6 MB
    u16*   neighB  = (u16*)  alloc((size_t)N * D * sizeof(u16));   // 25.6 MB
    uint2* edge    = (uint2*)alloc((size_t)E * sizeof(uint2));     // 6.4 MB
    uint2* temp    = (uint2*)alloc((size_t)E * sizeof(uint2));     // 6.4 MB
    u16*   Wb1     = (u16*)  alloc((size_t)D * 2 * D * sizeof(u16));
    u16*   Wb2     = (u16*)  alloc((size_t)D * 2 * D * sizeof(u16));
    int*   rowptr  = (int*)  alloc((size_t)(N + 1) * sizeof(int));
    int*   bCount  = (int*)  alloc((size_t)(nbuk + 1) * sizeof(int));
    int*   bBase   = (int*)  alloc((size_t)(nbuk + 1) * sizeof(int));
    int*   bCursor = (int*)  alloc((size_t)(nbuk + 1) * sizeof(int));

    const int gemmGrid = (N + 255) / 256;
    const int n4 = N * D / 4;
    const int w4 = D * 2 * D / 4;   // 8192

    // ---- Bucketed CSR build + casts ----
    hipMemsetAsync(bCount, 0, (size_t)nbuk * sizeof(int), stream);
    bucket_count    <<<256, 256, 0, stream>>>(src, bCount, E, nbuk);
    bucket_scan     <<<1, 1024, 0, stream>>>(bCount, bBase, bCursor, nbuk, E);
    partition_kernel<<<256, 256, 0, stream>>>(src, dst, ew, bCursor, temp, E, nbuk);
    bucket_csr      <<<nbuk, 256, 0, stream>>>(temp, bBase, rowptr, edge, N, E);
    cast_kernel     <<<(n4 + 255) / 256, 256, 0, stream>>>(x, xb, n4);
    cast_kernel     <<<(w4 + 255) / 256, 256, 0, stream>>>(W1, Wb1, w4);
    cast_kernel     <<<(w4 + 255) / 256, 256, 0, stream>>>(W2, Wb2, w4);

    // ---- Layer 1 ----
    aggregate_kernel<<<(N + 3) / 4, 256, 0, stream>>>(xb, rowptr, edge, neighB, N);
    sage_gemm<false><<<gemmGrid, 512, 0, stream>>>(xb, neighB, Wb1, b1, hB, nullptr, N);

    // ---- Layer 2 (normalize fused into epilogue) ----
    aggregate_kernel<<<(N + 3) / 4, 256, 0, stream>>>(hB, rowptr, edge, neighB, N);
    sage_gemm<true><<<gemmGrid, 512, 0, stream>>>(hB, neighB, Wb2, b2, nullptr, out, N);
}